// Round 6
// baseline (316.146 us; speedup 1.0000x reference)
//
#include <hip/hip_runtime.h>
#include <math.h>

#define N_LEVELS 24
#define CAPACITY 262144u
#define CAP_MASK 0x3FFFFu

typedef float vf2 __attribute__((ext_vector_type(2)));  // NT-builtin-compatible float2

struct ScaleArg { float s[N_LEVELS]; };

struct Prep {
    float w0, w1, w2, w3;
    unsigned i0, i1, i2, i3;
};

// Weights + hash indices for one (point, level). Bit-exact vs numpy f32 ref:
// no FMA contraction, IEEE divide, rintf == np.round (half-even).
__device__ __forceinline__ Prep permuto_prep(
    float p0, float p1, float p2,
    float scale, float s0, float s1, float s2)
{
#pragma clang fp contract(off)
    // f32(INV_STD_DEV / sqrt((i+1)*(i+2))), INV_STD_DEV = 4*sqrt(2/3)
    const float sf0 = 2.3094010767585034f;
    const float sf1 = 1.3333333333333335f;
    const float sf2 = 0.9428090415820634f;

    const float q0 = p0 / scale + s0;
    const float q1 = p1 / scale + s1;
    const float q2 = p2 / scale + s2;
    const float cf0 = q0 * sf0;
    const float cf1 = q1 * sf1;
    const float cf2 = q2 * sf2;

    const float rc1 = cf2 + cf1;
    const float el0 = rc1 + cf0;
    const float el1 = rc1 - cf0;
    const float el2 = cf2 - 2.0f * cf1;
    const float el3 = 0.0f - 3.0f * cf2;

    float r0 = rintf(el0 * 0.25f) * 4.0f;
    float r1 = rintf(el1 * 0.25f) * 4.0f;
    float r2 = rintf(el2 * 0.25f) * 4.0f;
    float r3 = rintf(el3 * 0.25f) * 4.0f;

    const float d0 = el0 - r0;
    const float d1 = el1 - r1;
    const float d2 = el2 - r2;
    const float d3 = el3 - r3;

    int k0 = 0, k1 = 0, k2 = 0, k3 = 0;
    if (d0 < d1) k0++; else k1++;
    if (d0 < d2) k0++; else k2++;
    if (d0 < d3) k0++; else k3++;
    if (d1 < d2) k1++; else k2++;
    if (d1 < d3) k1++; else k3++;
    if (d2 < d3) k2++; else k3++;

    const int s = (int)rintf((((r0 + r1) + r2) + r3) * 0.25f);
    k0 += s; k1 += s; k2 += s; k3 += s;

    if (k0 < 0) { k0 += 4; r0 += 4.0f; } else if (k0 > 3) { k0 -= 4; r0 -= 4.0f; }
    if (k1 < 0) { k1 += 4; r1 += 4.0f; } else if (k1 > 3) { k1 -= 4; r1 -= 4.0f; }
    if (k2 < 0) { k2 += 4; r2 += 4.0f; } else if (k2 > 3) { k2 -= 4; r2 -= 4.0f; }
    if (k3 < 0) { k3 += 4; r3 += 4.0f; } else if (k3 > 3) { k3 -= 4; r3 -= 4.0f; }

    const float dl0 = (el0 - r0) * 0.25f;
    const float dl1 = (el1 - r1) * 0.25f;
    const float dl2 = (el2 - r2) * 0.25f;
    const float dl3 = (el3 - r3) * 0.25f;

    const float g0 = (k0 == 0 ? dl0 : 0.0f) + (k1 == 0 ? dl1 : 0.0f) + (k2 == 0 ? dl2 : 0.0f) + (k3 == 0 ? dl3 : 0.0f);
    const float g1 = (k0 == 1 ? dl0 : 0.0f) + (k1 == 1 ? dl1 : 0.0f) + (k2 == 1 ? dl2 : 0.0f) + (k3 == 1 ? dl3 : 0.0f);
    const float g2 = (k0 == 2 ? dl0 : 0.0f) + (k1 == 2 ? dl1 : 0.0f) + (k2 == 2 ? dl2 : 0.0f) + (k3 == 2 ? dl3 : 0.0f);
    const float g3 = (k0 == 3 ? dl0 : 0.0f) + (k1 == 3 ? dl1 : 0.0f) + (k2 == 3 ? dl2 : 0.0f) + (k3 == 3 ? dl3 : 0.0f);

    Prep out;
    out.w0 = g3 + 1.0f - g0;
    out.w1 = g2 - g3;
    out.w2 = g1 - g2;
    out.w3 = g0 - g1;

    const int i0 = (int)r0;
    const int i1 = (int)r1;
    const int i2 = (int)r2;

    unsigned idx[4];
#pragma unroll
    for (int r = 0; r < 4; ++r) {
        const int key0 = i0 + r - ((k0 > 3 - r) ? 4 : 0);
        const int key1 = i1 + r - ((k1 > 3 - r) ? 4 : 0);
        const int key2 = i2 + r - ((k2 > 3 - r) ? 4 : 0);
        const unsigned hsh = (unsigned)key0 * 2654435761u
                           ^ (unsigned)key1 * 805459861u
                           ^ (unsigned)key2 * 3674653429u;
        idx[r] = hsh & CAP_MASK;
    }
    out.i0 = idx[0]; out.i1 = idx[1]; out.i2 = idx[2]; out.i3 = idx[3];
    return out;
}

// Pass 1: level-major gather, XCD affinity (blockIdx&7 -> levels {k,8+k,16+k}).
// NT table loads (no L1 allocate: L1 is 100%-miss on a 2MB random gather,
// allocation/eviction just serializes the TCP miss path). NT ws stores
// (bypass L2: keeps the level's 2MB table L2-resident instead of letting
// 2MB of write-allocate evict it to L3).
__global__ __launch_bounds__(256)
void permuto_gather(const float* __restrict__ pos,
                    const float* __restrict__ lattice,
                    const float* __restrict__ rshift,
                    const float* __restrict__ anneal,
                    vf2* __restrict__ ws,
                    ScaleArg sc, int npts, int chunksPerLevel)
{
#pragma clang fp contract(off)
    const int i = blockIdx.x;
    const int xcd = i & 7;
    const int j = i >> 3;
    const int phase = j / chunksPerLevel;        // 0..2
    const int chunk = j - phase * chunksPerLevel;
    const int level = phase * 8 + xcd;           // one coarse/mid/fine per XCD

    const int n = chunk * 256 + threadIdx.x;
    if (n >= npts) return;

    const float scale = sc.s[level];
    const float s0 = rshift[level * 3 + 0];      // wave-uniform -> scalar loads
    const float s1 = rshift[level * 3 + 1];
    const float s2 = rshift[level * 3 + 2];
    const float a  = anneal[level];

    const float p0 = __builtin_nontemporal_load(pos + n * 3 + 0);
    const float p1 = __builtin_nontemporal_load(pos + n * 3 + 1);
    const float p2 = __builtin_nontemporal_load(pos + n * 3 + 2);

    const vf2* __restrict__ tab = (const vf2*)lattice + (size_t)level * CAPACITY;

    Prep pr = permuto_prep(p0, p1, p2, scale, s0, s1, s2);

    // batched NT gathers: all 4 in flight before first use
    const vf2 v0 = __builtin_nontemporal_load(tab + pr.i0);
    const vf2 v1 = __builtin_nontemporal_load(tab + pr.i1);
    const vf2 v2 = __builtin_nontemporal_load(tab + pr.i2);
    const vf2 v3 = __builtin_nontemporal_load(tab + pr.i3);

    const float ax = pr.w0 * v0.x + pr.w1 * v1.x + pr.w2 * v2.x + pr.w3 * v3.x;
    const float ay = pr.w0 * v0.y + pr.w1 * v1.y + pr.w2 * v2.y + pr.w3 * v3.y;

    vf2 res; res.x = ax * a; res.y = ay * a;
    __builtin_nontemporal_store(res, ws + (size_t)level * npts + n);
}

// Pass 2: (L,N,2) -> (N,L,2) via LDS tile; global writes fully dense per instr.
__global__ __launch_bounds__(256)
void permuto_transpose(const vf2* __restrict__ ws,
                       float4* __restrict__ out, int npts)
{
    __shared__ vf2 sh[N_LEVELS][257];
    const int t = threadIdx.x;
    const int pbase = blockIdx.x * 256;
    const int valid = npts - pbase;

    if (valid >= 256) {
#pragma unroll
        for (int l = 0; l < N_LEVELS; ++l)
            sh[l][t] = __builtin_nontemporal_load(ws + (size_t)l * npts + pbase + t);
        __syncthreads();

        float4* o = out + (size_t)pbase * 12;
#pragma unroll
        for (int s = 0; s < 12; ++s) {
            const int q = s * 256 + t;     // float4 index within block tile
            const int p = q / 12;          // local point
            const int j = q - p * 12;      // float4-within-point = levels 2j,2j+1
            const vf2 va = sh[2 * j][p];
            const vf2 vb = sh[2 * j + 1][p];
            o[q] = make_float4(va.x, va.y, vb.x, vb.y);    // dense 16B/lane
        }
    } else {
        if (t < valid) {
            const int n = pbase + t;
            float4* o = out + (size_t)n * 12;
#pragma unroll
            for (int j = 0; j < 12; ++j) {
                const vf2 va = ws[(size_t)(2 * j) * npts + n];
                const vf2 vb = ws[(size_t)(2 * j + 1) * npts + n];
                o[j] = make_float4(va.x, va.y, vb.x, vb.y);
            }
        }
    }
}

// Fallback (ws too small): monolithic, one thread per point.
__global__ __launch_bounds__(256)
void permuto_mono(const float* __restrict__ pos,
                  const float* __restrict__ lattice,
                  const float* __restrict__ rshift,
                  const float* __restrict__ anneal,
                  float* __restrict__ out,
                  ScaleArg sc, int npts)
{
#pragma clang fp contract(off)
    __shared__ float sh_shift[N_LEVELS][3];
    __shared__ float sh_ann[N_LEVELS];
    const int tid = threadIdx.x;
    if (tid < N_LEVELS) {
        sh_shift[tid][0] = rshift[tid * 3 + 0];
        sh_shift[tid][1] = rshift[tid * 3 + 1];
        sh_shift[tid][2] = rshift[tid * 3 + 2];
        sh_ann[tid] = anneal[tid];
    }
    __syncthreads();

    const int n = blockIdx.x * 256 + tid;
    if (n >= npts) return;
    const float p0 = pos[n * 3 + 0];
    const float p1 = pos[n * 3 + 1];
    const float p2 = pos[n * 3 + 2];
    float2* outv = (float2*)out + (size_t)n * N_LEVELS;
    for (int l = 0; l < N_LEVELS; ++l) {
        const float2* tab = (const float2*)lattice + (size_t)l * CAPACITY;
        Prep pr = permuto_prep(p0, p1, p2, sc.s[l],
                               sh_shift[l][0], sh_shift[l][1], sh_shift[l][2]);
        float2 v0 = tab[pr.i0], v1 = tab[pr.i1], v2 = tab[pr.i2], v3 = tab[pr.i3];
        float ax = pr.w0 * v0.x + pr.w1 * v1.x + pr.w2 * v2.x + pr.w3 * v3.x;
        float ay = pr.w0 * v0.y + pr.w1 * v1.y + pr.w2 * v2.y + pr.w3 * v3.y;
        outv[l] = make_float2(ax * sh_ann[l], ay * sh_ann[l]);
    }
}

extern "C" void kernel_launch(void* const* d_in, const int* in_sizes, int n_in,
                              void* d_out, int out_size, void* d_ws, size_t ws_size,
                              hipStream_t stream) {
    const float* pos     = (const float*)d_in[0];
    const float* lattice = (const float*)d_in[1];
    const float* rshift  = (const float*)d_in[2];
    const float* anneal  = (const float*)d_in[3];
    const int npts = in_sizes[0] / 3;

    // np.geomspace(1.0, 1e-4, 24).astype(f32): 10**(i * (-4/23)), endpoints pinned
    ScaleArg sc;
    for (int i = 0; i < N_LEVELS; ++i)
        sc.s[i] = (float)pow(10.0, (double)i * (-4.0 / 23.0));
    sc.s[0] = 1.0f;
    sc.s[N_LEVELS - 1] = 1e-4f;

    const size_t ws_need = (size_t)N_LEVELS * (size_t)npts * sizeof(vf2);
    if (ws_size >= ws_need) {
        const int C = (npts + 255) / 256;          // 256-point chunks per level
        const int blocks1 = 8 * 3 * C;             // 24 * C, xcd-swizzled
        permuto_gather<<<blocks1, 256, 0, stream>>>(
            pos, lattice, rshift, anneal, (vf2*)d_ws, sc, npts, C);
        const int blocks2 = (npts + 255) / 256;
        permuto_transpose<<<blocks2, 256, 0, stream>>>(
            (const vf2*)d_ws, (float4*)d_out, npts);
    } else {
        const int blocks = (npts + 255) / 256;
        permuto_mono<<<blocks, 256, 0, stream>>>(
            pos, lattice, rshift, anneal, (float*)d_out, sc, npts);
    }
}

// Round 7
// 217.368 us; speedup vs baseline: 1.4544x; 1.4544x over previous
//
#include <hip/hip_runtime.h>
#include <math.h>

#define N_LEVELS 24
#define CAPACITY 262144u
#define CAP_MASK 0x3FFFFu

struct ScaleArg { float s[N_LEVELS]; };

struct Prep {
    float w0, w1, w2, w3;
    unsigned i0, i1, i2, i3;
};

// Weights + hash indices for one (point, level). Bit-exact vs numpy f32 ref:
// no FMA contraction, IEEE divide, rintf == np.round (half-even).
__device__ __forceinline__ Prep permuto_prep(
    float p0, float p1, float p2,
    float scale, float s0, float s1, float s2)
{
#pragma clang fp contract(off)
    // f32(INV_STD_DEV / sqrt((i+1)*(i+2))), INV_STD_DEV = 4*sqrt(2/3)
    const float sf0 = 2.3094010767585034f;
    const float sf1 = 1.3333333333333335f;
    const float sf2 = 0.9428090415820634f;

    const float q0 = p0 / scale + s0;
    const float q1 = p1 / scale + s1;
    const float q2 = p2 / scale + s2;
    const float cf0 = q0 * sf0;
    const float cf1 = q1 * sf1;
    const float cf2 = q2 * sf2;

    const float rc1 = cf2 + cf1;
    const float el0 = rc1 + cf0;
    const float el1 = rc1 - cf0;
    const float el2 = cf2 - 2.0f * cf1;
    const float el3 = 0.0f - 3.0f * cf2;

    float r0 = rintf(el0 * 0.25f) * 4.0f;
    float r1 = rintf(el1 * 0.25f) * 4.0f;
    float r2 = rintf(el2 * 0.25f) * 4.0f;
    float r3 = rintf(el3 * 0.25f) * 4.0f;

    const float d0 = el0 - r0;
    const float d1 = el1 - r1;
    const float d2 = el2 - r2;
    const float d3 = el3 - r3;

    int k0 = 0, k1 = 0, k2 = 0, k3 = 0;
    if (d0 < d1) k0++; else k1++;
    if (d0 < d2) k0++; else k2++;
    if (d0 < d3) k0++; else k3++;
    if (d1 < d2) k1++; else k2++;
    if (d1 < d3) k1++; else k3++;
    if (d2 < d3) k2++; else k3++;

    const int s = (int)rintf((((r0 + r1) + r2) + r3) * 0.25f);
    k0 += s; k1 += s; k2 += s; k3 += s;

    if (k0 < 0) { k0 += 4; r0 += 4.0f; } else if (k0 > 3) { k0 -= 4; r0 -= 4.0f; }
    if (k1 < 0) { k1 += 4; r1 += 4.0f; } else if (k1 > 3) { k1 -= 4; r1 -= 4.0f; }
    if (k2 < 0) { k2 += 4; r2 += 4.0f; } else if (k2 > 3) { k2 -= 4; r2 -= 4.0f; }
    if (k3 < 0) { k3 += 4; r3 += 4.0f; } else if (k3 > 3) { k3 -= 4; r3 -= 4.0f; }

    const float dl0 = (el0 - r0) * 0.25f;
    const float dl1 = (el1 - r1) * 0.25f;
    const float dl2 = (el2 - r2) * 0.25f;
    const float dl3 = (el3 - r3) * 0.25f;

    const float g0 = (k0 == 0 ? dl0 : 0.0f) + (k1 == 0 ? dl1 : 0.0f) + (k2 == 0 ? dl2 : 0.0f) + (k3 == 0 ? dl3 : 0.0f);
    const float g1 = (k0 == 1 ? dl0 : 0.0f) + (k1 == 1 ? dl1 : 0.0f) + (k2 == 1 ? dl2 : 0.0f) + (k3 == 1 ? dl3 : 0.0f);
    const float g2 = (k0 == 2 ? dl0 : 0.0f) + (k1 == 2 ? dl1 : 0.0f) + (k2 == 2 ? dl2 : 0.0f) + (k3 == 2 ? dl3 : 0.0f);
    const float g3 = (k0 == 3 ? dl0 : 0.0f) + (k1 == 3 ? dl1 : 0.0f) + (k2 == 3 ? dl2 : 0.0f) + (k3 == 3 ? dl3 : 0.0f);

    Prep out;
    out.w0 = g3 + 1.0f - g0;
    out.w1 = g2 - g3;
    out.w2 = g1 - g2;
    out.w3 = g0 - g1;

    const int i0 = (int)r0;
    const int i1 = (int)r1;
    const int i2 = (int)r2;

    unsigned idx[4];
#pragma unroll
    for (int r = 0; r < 4; ++r) {
        const int key0 = i0 + r - ((k0 > 3 - r) ? 4 : 0);
        const int key1 = i1 + r - ((k1 > 3 - r) ? 4 : 0);
        const int key2 = i2 + r - ((k2 > 3 - r) ? 4 : 0);
        const unsigned hsh = (unsigned)key0 * 2654435761u
                           ^ (unsigned)key1 * 805459861u
                           ^ (unsigned)key2 * 3674653429u;
        idx[r] = hsh & CAP_MASK;
    }
    out.i0 = idx[0]; out.i1 = idx[1]; out.i2 = idx[2]; out.i3 = idx[3];
    return out;
}

// Pass 1: level-major gather, XCD affinity via blockIdx&7, cost-balanced
// schedule (npts==262144, 1024 chunks/level of 256 pts):
//  - fine levels 10..23 (random-hash regime, ~equal cost): each split into 4
//    quarters of 256 chunks; 56 quarters round-robined -> exactly 7 per XCD.
//    (Each fine table is then read by 4 XCDs; refetches hit L3, not HBM.)
//  - cheap levels 0..9 (within-wave line merging makes them ~free): level k->
//    XCD k for k<8; level 9 -> XCD 0, level 8 -> XCD 1.
// Plain loads everywhere: NT proved to kill L2/L3 residency (R6: FETCH 54->354MB).
__global__ __launch_bounds__(256)
void permuto_gather(const float* __restrict__ pos,
                    const float* __restrict__ lattice,
                    const float* __restrict__ rshift,
                    const float* __restrict__ anneal,
                    float2* __restrict__ ws,
                    ScaleArg sc, int npts, int balanced, int chunksPerLevel)
{
#pragma clang fp contract(off)
    int level, chunk;
    const int xcd = blockIdx.x & 7;
    if (balanced) {
        const int slot = blockIdx.x >> 3;
        if (slot < 1792) {                 // fine quarters
            const int j = slot >> 8;       // 0..6
            const int q = j * 8 + xcd;     // 0..55
            level = 10 + (q >> 2);
            chunk = ((q & 3) << 8) + (slot & 255);
        } else {                           // cheap levels
            const int c = slot - 1792;     // 0..2047
            const int second = c >> 10;    // 0,1
            if (second == 0)      level = xcd;
            else if (xcd == 0)    level = 9;
            else if (xcd == 1)    level = 8;
            else return;                   // idle pad block
            chunk = c & 1023;
        }
    } else {
        const int j = blockIdx.x >> 3;
        const int phase = j / chunksPerLevel;
        chunk = j - phase * chunksPerLevel;
        level = phase * 8 + xcd;
    }

    const int n = chunk * 256 + threadIdx.x;
    if (n >= npts) return;

    const float scale = sc.s[level];
    const float s0 = rshift[level * 3 + 0];      // wave-uniform -> scalar loads
    const float s1 = rshift[level * 3 + 1];
    const float s2 = rshift[level * 3 + 2];
    const float a  = anneal[level];

    const float p0 = pos[n * 3 + 0];
    const float p1 = pos[n * 3 + 1];
    const float p2 = pos[n * 3 + 2];

    const float2* __restrict__ tab = (const float2*)lattice + (size_t)level * CAPACITY;

    Prep pr = permuto_prep(p0, p1, p2, scale, s0, s1, s2);

    // batched gathers: all 4 in flight before first use
    const float2 v0 = tab[pr.i0];
    const float2 v1 = tab[pr.i1];
    const float2 v2 = tab[pr.i2];
    const float2 v3 = tab[pr.i3];

    const float ax = pr.w0 * v0.x + pr.w1 * v1.x + pr.w2 * v2.x + pr.w3 * v3.x;
    const float ay = pr.w0 * v0.y + pr.w1 * v1.y + pr.w2 * v2.y + pr.w3 * v3.y;

    ws[(size_t)level * npts + n] = make_float2(ax * a, ay * a);
}

// Pass 2: (L,N,2) -> (N,L,2) via LDS tile; global writes fully dense per instr.
__global__ __launch_bounds__(256)
void permuto_transpose(const float2* __restrict__ ws,
                       float4* __restrict__ out, int npts)
{
    __shared__ float2 sh[N_LEVELS][257];
    const int t = threadIdx.x;
    const int pbase = blockIdx.x * 256;
    const int valid = npts - pbase;

    if (valid >= 256) {
#pragma unroll
        for (int l = 0; l < N_LEVELS; ++l)
            sh[l][t] = ws[(size_t)l * npts + pbase + t];
        __syncthreads();

        float4* o = out + (size_t)pbase * 12;
#pragma unroll
        for (int s = 0; s < 12; ++s) {
            const int q = s * 256 + t;     // float4 index within block tile
            const int p = q / 12;          // local point
            const int j = q - p * 12;      // float4-within-point = levels 2j,2j+1
            const float2 va = sh[2 * j][p];
            const float2 vb = sh[2 * j + 1][p];
            o[q] = make_float4(va.x, va.y, vb.x, vb.y);    // dense 16B/lane
        }
    } else {
        if (t < valid) {
            const int n = pbase + t;
            float4* o = out + (size_t)n * 12;
#pragma unroll
            for (int j = 0; j < 12; ++j) {
                const float2 va = ws[(size_t)(2 * j) * npts + n];
                const float2 vb = ws[(size_t)(2 * j + 1) * npts + n];
                o[j] = make_float4(va.x, va.y, vb.x, vb.y);
            }
        }
    }
}

// Fallback (ws too small): monolithic, one thread per point.
__global__ __launch_bounds__(256)
void permuto_mono(const float* __restrict__ pos,
                  const float* __restrict__ lattice,
                  const float* __restrict__ rshift,
                  const float* __restrict__ anneal,
                  float* __restrict__ out,
                  ScaleArg sc, int npts)
{
#pragma clang fp contract(off)
    __shared__ float sh_shift[N_LEVELS][3];
    __shared__ float sh_ann[N_LEVELS];
    const int tid = threadIdx.x;
    if (tid < N_LEVELS) {
        sh_shift[tid][0] = rshift[tid * 3 + 0];
        sh_shift[tid][1] = rshift[tid * 3 + 1];
        sh_shift[tid][2] = rshift[tid * 3 + 2];
        sh_ann[tid] = anneal[tid];
    }
    __syncthreads();

    const int n = blockIdx.x * 256 + tid;
    if (n >= npts) return;
    const float p0 = pos[n * 3 + 0];
    const float p1 = pos[n * 3 + 1];
    const float p2 = pos[n * 3 + 2];
    float2* outv = (float2*)out + (size_t)n * N_LEVELS;
    for (int l = 0; l < N_LEVELS; ++l) {
        const float2* tab = (const float2*)lattice + (size_t)l * CAPACITY;
        Prep pr = permuto_prep(p0, p1, p2, sc.s[l],
                               sh_shift[l][0], sh_shift[l][1], sh_shift[l][2]);
        float2 v0 = tab[pr.i0], v1 = tab[pr.i1], v2 = tab[pr.i2], v3 = tab[pr.i3];
        float ax = pr.w0 * v0.x + pr.w1 * v1.x + pr.w2 * v2.x + pr.w3 * v3.x;
        float ay = pr.w0 * v0.y + pr.w1 * v1.y + pr.w2 * v2.y + pr.w3 * v3.y;
        outv[l] = make_float2(ax * sh_ann[l], ay * sh_ann[l]);
    }
}

extern "C" void kernel_launch(void* const* d_in, const int* in_sizes, int n_in,
                              void* d_out, int out_size, void* d_ws, size_t ws_size,
                              hipStream_t stream) {
    const float* pos     = (const float*)d_in[0];
    const float* lattice = (const float*)d_in[1];
    const float* rshift  = (const float*)d_in[2];
    const float* anneal  = (const float*)d_in[3];
    const int npts = in_sizes[0] / 3;

    // np.geomspace(1.0, 1e-4, 24).astype(f32): 10**(i * (-4/23)), endpoints pinned
    ScaleArg sc;
    for (int i = 0; i < N_LEVELS; ++i)
        sc.s[i] = (float)pow(10.0, (double)i * (-4.0 / 23.0));
    sc.s[0] = 1.0f;
    sc.s[N_LEVELS - 1] = 1e-4f;

    const size_t ws_need = (size_t)N_LEVELS * (size_t)npts * sizeof(float2);
    if (ws_size >= ws_need) {
        const int C = (npts + 255) / 256;          // chunks per level
        if (C == 1024) {
            // balanced schedule: 8 XCD lanes x 3840 slots
            permuto_gather<<<8 * 3840, 256, 0, stream>>>(
                pos, lattice, rshift, anneal, (float2*)d_ws, sc, npts, 1, C);
        } else {
            permuto_gather<<<8 * 3 * C, 256, 0, stream>>>(
                pos, lattice, rshift, anneal, (float2*)d_ws, sc, npts, 0, C);
        }
        const int blocks2 = (npts + 255) / 256;
        permuto_transpose<<<blocks2, 256, 0, stream>>>(
            (const float2*)d_ws, (float4*)d_out, npts);
    } else {
        const int blocks = (npts + 255) / 256;
        permuto_mono<<<blocks, 256, 0, stream>>>(
            pos, lattice, rshift, anneal, (float*)d_out, sc, npts);
    }
}

// Round 8
// 196.988 us; speedup vs baseline: 1.6049x; 1.1035x over previous
//
#include <hip/hip_runtime.h>
#include <math.h>

#define N_LEVELS 24
#define CAPACITY 262144u
#define CAP_MASK 0x3FFFFu

struct ScaleArg { float s[N_LEVELS]; };

struct Prep {
    float w0, w1, w2, w3;
    unsigned i0, i1, i2, i3;
};

// Weights + hash indices for one (point, level). Bit-exact vs numpy f32 ref:
// no FMA contraction, IEEE divide, rintf == np.round (half-even).
__device__ __forceinline__ Prep permuto_prep(
    float p0, float p1, float p2,
    float scale, float s0, float s1, float s2)
{
#pragma clang fp contract(off)
    // f32(INV_STD_DEV / sqrt((i+1)*(i+2))), INV_STD_DEV = 4*sqrt(2/3)
    const float sf0 = 2.3094010767585034f;
    const float sf1 = 1.3333333333333335f;
    const float sf2 = 0.9428090415820634f;

    const float q0 = p0 / scale + s0;
    const float q1 = p1 / scale + s1;
    const float q2 = p2 / scale + s2;
    const float cf0 = q0 * sf0;
    const float cf1 = q1 * sf1;
    const float cf2 = q2 * sf2;

    const float rc1 = cf2 + cf1;
    const float el0 = rc1 + cf0;
    const float el1 = rc1 - cf0;
    const float el2 = cf2 - 2.0f * cf1;
    const float el3 = 0.0f - 3.0f * cf2;

    float r0 = rintf(el0 * 0.25f) * 4.0f;
    float r1 = rintf(el1 * 0.25f) * 4.0f;
    float r2 = rintf(el2 * 0.25f) * 4.0f;
    float r3 = rintf(el3 * 0.25f) * 4.0f;

    const float d0 = el0 - r0;
    const float d1 = el1 - r1;
    const float d2 = el2 - r2;
    const float d3 = el3 - r3;

    int k0 = 0, k1 = 0, k2 = 0, k3 = 0;
    if (d0 < d1) k0++; else k1++;
    if (d0 < d2) k0++; else k2++;
    if (d0 < d3) k0++; else k3++;
    if (d1 < d2) k1++; else k2++;
    if (d1 < d3) k1++; else k3++;
    if (d2 < d3) k2++; else k3++;

    const int s = (int)rintf((((r0 + r1) + r2) + r3) * 0.25f);
    k0 += s; k1 += s; k2 += s; k3 += s;

    if (k0 < 0) { k0 += 4; r0 += 4.0f; } else if (k0 > 3) { k0 -= 4; r0 -= 4.0f; }
    if (k1 < 0) { k1 += 4; r1 += 4.0f; } else if (k1 > 3) { k1 -= 4; r1 -= 4.0f; }
    if (k2 < 0) { k2 += 4; r2 += 4.0f; } else if (k2 > 3) { k2 -= 4; r2 -= 4.0f; }
    if (k3 < 0) { k3 += 4; r3 += 4.0f; } else if (k3 > 3) { k3 -= 4; r3 -= 4.0f; }

    const float dl0 = (el0 - r0) * 0.25f;
    const float dl1 = (el1 - r1) * 0.25f;
    const float dl2 = (el2 - r2) * 0.25f;
    const float dl3 = (el3 - r3) * 0.25f;

    const float g0 = (k0 == 0 ? dl0 : 0.0f) + (k1 == 0 ? dl1 : 0.0f) + (k2 == 0 ? dl2 : 0.0f) + (k3 == 0 ? dl3 : 0.0f);
    const float g1 = (k0 == 1 ? dl0 : 0.0f) + (k1 == 1 ? dl1 : 0.0f) + (k2 == 1 ? dl2 : 0.0f) + (k3 == 1 ? dl3 : 0.0f);
    const float g2 = (k0 == 2 ? dl0 : 0.0f) + (k1 == 2 ? dl1 : 0.0f) + (k2 == 2 ? dl2 : 0.0f) + (k3 == 2 ? dl3 : 0.0f);
    const float g3 = (k0 == 3 ? dl0 : 0.0f) + (k1 == 3 ? dl1 : 0.0f) + (k2 == 3 ? dl2 : 0.0f) + (k3 == 3 ? dl3 : 0.0f);

    Prep out;
    out.w0 = g3 + 1.0f - g0;
    out.w1 = g2 - g3;
    out.w2 = g1 - g2;
    out.w3 = g0 - g1;

    const int i0 = (int)r0;
    const int i1 = (int)r1;
    const int i2 = (int)r2;

    unsigned idx[4];
#pragma unroll
    for (int r = 0; r < 4; ++r) {
        const int key0 = i0 + r - ((k0 > 3 - r) ? 4 : 0);
        const int key1 = i1 + r - ((k1 > 3 - r) ? 4 : 0);
        const int key2 = i2 + r - ((k2 > 3 - r) ? 4 : 0);
        const unsigned hsh = (unsigned)key0 * 2654435761u
                           ^ (unsigned)key1 * 805459861u
                           ^ (unsigned)key2 * 3674653429u;
        idx[r] = hsh & CAP_MASK;
    }
    out.i0 = idx[0]; out.i1 = idx[1]; out.i2 = idx[2]; out.i3 = idx[3];
    return out;
}

// Pass 1: level-major gather with XCD affinity (xcd = blockIdx&7).
// Cost model (R7 post-mortem): per-level cost is set by L1 hit rate; heavy
// levels are 8..23 (hash-scattered footprint >= 760KB, ~full L1 miss),
// levels 0..7 have footprints <= 290KB (total ~1.5MB -> cross-XCD
// duplication is free). Schedule (npts==262144, 1024 chunks/level):
//   phase A (slot 0..1023):    level 8+xcd,  whole table, L2-resident
//   phase B (slot 1024..2047): level 16+xcd, whole table, L2-resident
//   phase C (slot 2048..3071): levels 0..7 sliced over all XCDs
// -> per-XCD load ~2.2 heavy-units vs R3's critical 2.9 (XCD7: 7,15,23).
// Plain loads only: NT kills L2/L3 residency (R6: FETCH 54->354MB).
__global__ __launch_bounds__(256)
void permuto_gather(const float* __restrict__ pos,
                    const float* __restrict__ lattice,
                    const float* __restrict__ rshift,
                    const float* __restrict__ anneal,
                    float2* __restrict__ ws,
                    ScaleArg sc, int npts, int balanced, int chunksPerLevel)
{
#pragma clang fp contract(off)
    int level, chunk;
    const int xcd = blockIdx.x & 7;
    if (balanced) {
        const int slot = blockIdx.x >> 3;
        if (slot < 1024)      { level = 8 + xcd;  chunk = slot; }
        else if (slot < 2048) { level = 16 + xcd; chunk = slot - 1024; }
        else {
            const int s = slot - 2048;          // 0..1023
            level = s & 7;                      // cheap levels 0..7
            chunk = (s & ~7) | xcd;             // covers all 1024 chunks/level
        }
    } else {
        const int j = blockIdx.x >> 3;
        const int phase = j / chunksPerLevel;
        chunk = j - phase * chunksPerLevel;
        level = phase * 8 + xcd;
    }

    const int n = chunk * 256 + threadIdx.x;
    if (n >= npts) return;

    const float scale = sc.s[level];
    const float s0 = rshift[level * 3 + 0];      // wave-uniform -> scalar loads
    const float s1 = rshift[level * 3 + 1];
    const float s2 = rshift[level * 3 + 2];
    const float a  = anneal[level];

    const float p0 = pos[n * 3 + 0];
    const float p1 = pos[n * 3 + 1];
    const float p2 = pos[n * 3 + 2];

    const float2* __restrict__ tab = (const float2*)lattice + (size_t)level * CAPACITY;

    Prep pr = permuto_prep(p0, p1, p2, scale, s0, s1, s2);

    // batched gathers: all 4 in flight before first use
    const float2 v0 = tab[pr.i0];
    const float2 v1 = tab[pr.i1];
    const float2 v2 = tab[pr.i2];
    const float2 v3 = tab[pr.i3];

    const float ax = pr.w0 * v0.x + pr.w1 * v1.x + pr.w2 * v2.x + pr.w3 * v3.x;
    const float ay = pr.w0 * v0.y + pr.w1 * v1.y + pr.w2 * v2.y + pr.w3 * v3.y;

    ws[(size_t)level * npts + n] = make_float2(ax * a, ay * a);
}

// Pass 2: (L,N,2) -> (N,L,2) via LDS tile; global writes fully dense per instr.
__global__ __launch_bounds__(256)
void permuto_transpose(const float2* __restrict__ ws,
                       float4* __restrict__ out, int npts)
{
    __shared__ float2 sh[N_LEVELS][257];
    const int t = threadIdx.x;
    const int pbase = blockIdx.x * 256;
    const int valid = npts - pbase;

    if (valid >= 256) {
#pragma unroll
        for (int l = 0; l < N_LEVELS; ++l)
            sh[l][t] = ws[(size_t)l * npts + pbase + t];
        __syncthreads();

        float4* o = out + (size_t)pbase * 12;
#pragma unroll
        for (int s = 0; s < 12; ++s) {
            const int q = s * 256 + t;     // float4 index within block tile
            const int p = q / 12;          // local point
            const int j = q - p * 12;      // float4-within-point = levels 2j,2j+1
            const float2 va = sh[2 * j][p];
            const float2 vb = sh[2 * j + 1][p];
            o[q] = make_float4(va.x, va.y, vb.x, vb.y);    // dense 16B/lane
        }
    } else {
        if (t < valid) {
            const int n = pbase + t;
            float4* o = out + (size_t)n * 12;
#pragma unroll
            for (int j = 0; j < 12; ++j) {
                const float2 va = ws[(size_t)(2 * j) * npts + n];
                const float2 vb = ws[(size_t)(2 * j + 1) * npts + n];
                o[j] = make_float4(va.x, va.y, vb.x, vb.y);
            }
        }
    }
}

// Fallback (ws too small): monolithic, one thread per point.
__global__ __launch_bounds__(256)
void permuto_mono(const float* __restrict__ pos,
                  const float* __restrict__ lattice,
                  const float* __restrict__ rshift,
                  const float* __restrict__ anneal,
                  float* __restrict__ out,
                  ScaleArg sc, int npts)
{
#pragma clang fp contract(off)
    __shared__ float sh_shift[N_LEVELS][3];
    __shared__ float sh_ann[N_LEVELS];
    const int tid = threadIdx.x;
    if (tid < N_LEVELS) {
        sh_shift[tid][0] = rshift[tid * 3 + 0];
        sh_shift[tid][1] = rshift[tid * 3 + 1];
        sh_shift[tid][2] = rshift[tid * 3 + 2];
        sh_ann[tid] = anneal[tid];
    }
    __syncthreads();

    const int n = blockIdx.x * 256 + tid;
    if (n >= npts) return;
    const float p0 = pos[n * 3 + 0];
    const float p1 = pos[n * 3 + 1];
    const float p2 = pos[n * 3 + 2];
    float2* outv = (float2*)out + (size_t)n * N_LEVELS;
    for (int l = 0; l < N_LEVELS; ++l) {
        const float2* tab = (const float2*)lattice + (size_t)l * CAPACITY;
        Prep pr = permuto_prep(p0, p1, p2, sc.s[l],
                               sh_shift[l][0], sh_shift[l][1], sh_shift[l][2]);
        float2 v0 = tab[pr.i0], v1 = tab[pr.i1], v2 = tab[pr.i2], v3 = tab[pr.i3];
        float ax = pr.w0 * v0.x + pr.w1 * v1.x + pr.w2 * v2.x + pr.w3 * v3.x;
        float ay = pr.w0 * v0.y + pr.w1 * v1.y + pr.w2 * v2.y + pr.w3 * v3.y;
        outv[l] = make_float2(ax * sh_ann[l], ay * sh_ann[l]);
    }
}

extern "C" void kernel_launch(void* const* d_in, const int* in_sizes, int n_in,
                              void* d_out, int out_size, void* d_ws, size_t ws_size,
                              hipStream_t stream) {
    const float* pos     = (const float*)d_in[0];
    const float* lattice = (const float*)d_in[1];
    const float* rshift  = (const float*)d_in[2];
    const float* anneal  = (const float*)d_in[3];
    const int npts = in_sizes[0] / 3;

    // np.geomspace(1.0, 1e-4, 24).astype(f32): 10**(i * (-4/23)), endpoints pinned
    ScaleArg sc;
    for (int i = 0; i < N_LEVELS; ++i)
        sc.s[i] = (float)pow(10.0, (double)i * (-4.0 / 23.0));
    sc.s[0] = 1.0f;
    sc.s[N_LEVELS - 1] = 1e-4f;

    const size_t ws_need = (size_t)N_LEVELS * (size_t)npts * sizeof(float2);
    if (ws_size >= ws_need) {
        const int C = (npts + 255) / 256;          // chunks per level
        if (C == 1024) {
            // balanced schedule: 8 XCD lanes x 3072 slots (A:8+x, B:16+x, C:0..7 sliced)
            permuto_gather<<<8 * 3072, 256, 0, stream>>>(
                pos, lattice, rshift, anneal, (float2*)d_ws, sc, npts, 1, C);
        } else {
            permuto_gather<<<8 * 3 * C, 256, 0, stream>>>(
                pos, lattice, rshift, anneal, (float2*)d_ws, sc, npts, 0, C);
        }
        const int blocks2 = (npts + 255) / 256;
        permuto_transpose<<<blocks2, 256, 0, stream>>>(
            (const float2*)d_ws, (float4*)d_out, npts);
    } else {
        const int blocks = (npts + 255) / 256;
        permuto_mono<<<blocks, 256, 0, stream>>>(
            pos, lattice, rshift, anneal, (float*)d_out, sc, npts);
    }
}